// Round 12
// baseline (33.984 us; speedup 1.0000x reference)
//
#include <hip/hip_runtime.h>
#include <math.h>

// ChamferLoss: pc_src [B,3,M] f32, pc_dst [B,3,N] f32 -> scalar mean over (B,M)
// of min_n ||src_m - dst_n||.
//
// MFMA engine (R11) + locality fixes (R12):
// d2p(n,m) = |d_n|^2 - 2 s_m . d_n as ONE K-column of v_mfma_f32_32x32x16_f16
// (split-f16: per coord uh*sh, uh*sl, ul*sh with u=-2d; plus (wh,wl)*1; 11/16
// K-slots; d2 err ~3e-5 -> absmax 0.0 measured in R11).
//
// R11 -> R12: (1) block-index layout puts (sg,b) in LOW 6 bits, srcgrp HIGH,
// so a CU's co-resident blocks (stride-256 apart) share ONE 16 KB A-slice ->
// L1-resident (R11 had sg in low bits: 8 distinct 32KB slices thrashed L1,
// 256 MB from L2 = the ~21us minseg). (2) 4 B-frags per wave: 4 MFMAs
// amortize each A-load -> MFMA-bound. (3) prep split by side (2x blocks);
// finish re-gridded 256x128.

#define TPB 256

constexpr int NB = 4;
constexpr int NM = 8192;
constexpr int NN = 8192;
constexpr int NPTS = NB * NM;                     // 32768
constexpr int NSEG = 16;                          // dst segments
constexpr int DSEG = NN / NSEG;                   // 512 dst per segment
constexpr int TILES = DSEG / 32;                  // 16 MFMA tiles per wave
constexpr int NSRCG = NM / 512;                   // 16 src groups (512 cols/blk)
constexpr int FIN_TPB = 128;
constexpr int NBLK_F = NPTS / FIN_TPB;            // 256 finish blocks

typedef _Float16 half8 __attribute__((ext_vector_type(8)));
typedef float f32x16 __attribute__((ext_vector_type(16)));

// Order-preserving float<->uint encode so unsigned atomicMin == float min.
__device__ __forceinline__ unsigned enc_f32(float f) {
    unsigned u = __float_as_uint(f);
    return (u & 0x80000000u) ? ~u : (u | 0x80000000u);
}
__device__ __forceinline__ float dec_f32(unsigned u) {
    unsigned b = (u & 0x80000000u) ? (u ^ 0x80000000u) : ~u;
    return __uint_as_float(b);
}
__device__ __forceinline__ float min3(float a, float b, float c) {
    return fminf(fminf(a, b), c);                 // -> v_min3_f32
}
// min of 16 C-regs folded into acc (covers all 32 rows across lane halves).
__device__ __forceinline__ float tile_min(const f32x16& c, float acc) {
    float v0 = min3(c[0],  c[1],  c[2]);
    float v1 = min3(c[3],  c[4],  c[5]);
    float v2 = min3(c[6],  c[7],  c[8]);
    float v3 = min3(c[9],  c[10], c[11]);
    float v4 = min3(c[12], c[13], c[14]);
    float w0 = min3(v0, v1, c[15]);
    float w1 = min3(v2, v3, v4);
    return min3(acc, w0, w1);
}

// Kernel 0: pack per-point MFMA fragments (16 f16 = 32 B each side); init
// minenc / sum cells. One side per thread (2*NPTS threads).
// A (dst d; u=-2d, w=|d|^2): [uhx uhx ulx uhy uhy uly uhz uhz | ulz wh wl 0..]
// B (src s):                 [shx slx shx shy sly shy shz slz | shz  1  1 0..]
__global__ __launch_bounds__(TPB) void prep_kernel(const float* __restrict__ src,
                                                   const float* __restrict__ dst,
                                                   char* __restrict__ dstfrag,
                                                   char* __restrict__ srcfrag,
                                                   unsigned* __restrict__ minenc,
                                                   unsigned long long* __restrict__ sumfix,
                                                   unsigned* __restrict__ ticket) {
    int idx = blockIdx.x * TPB + threadIdx.x;     // 0..2*NPTS
    if (idx == 0) { *sumfix = 0ULL; *ticket = 0u; }
    if (idx < NPTS) {                             // dst side
        minenc[idx] = 0xFFFFFFFFu;                // encodes > +inf
        int b = idx >> 13, n = idx & (NN - 1);
        const float* p = dst + (size_t)b * 3 * NN;
        float x = p[n], y = p[NN + n], z = p[2 * NN + n];
        float ux = -2.0f * x, uy = -2.0f * y, uz = -2.0f * z;
        float w = fmaf(x, x, fmaf(y, y, z * z));
        _Float16 uhx = (_Float16)ux; _Float16 ulx = (_Float16)(ux - (float)uhx);
        _Float16 uhy = (_Float16)uy; _Float16 uly = (_Float16)(uy - (float)uhy);
        _Float16 uhz = (_Float16)uz; _Float16 ulz = (_Float16)(uz - (float)uhz);
        _Float16 wh  = (_Float16)w;  _Float16 wl  = (_Float16)(w - (float)wh);
        half8 a0 = {uhx, uhx, ulx, uhy, uhy, uly, uhz, uhz};
        half8 a1 = {ulz, wh, wl, (_Float16)0.f, (_Float16)0.f,
                    (_Float16)0.f, (_Float16)0.f, (_Float16)0.f};
        *(half8*)(dstfrag + (size_t)idx * 32)      = a0;
        *(half8*)(dstfrag + (size_t)idx * 32 + 16) = a1;
    } else {                                      // src side
        int i2 = idx - NPTS;
        int b = i2 >> 13, n = i2 & (NM - 1);
        const float* p = src + (size_t)b * 3 * NM;
        float x = p[n], y = p[NM + n], z = p[2 * NM + n];
        _Float16 shx = (_Float16)x; _Float16 slx = (_Float16)(x - (float)shx);
        _Float16 shy = (_Float16)y; _Float16 sly = (_Float16)(y - (float)shy);
        _Float16 shz = (_Float16)z; _Float16 slz = (_Float16)(z - (float)shz);
        half8 b0 = {shx, slx, shx, shy, sly, shy, shz, slz};
        half8 b1 = {shz, (_Float16)1.f, (_Float16)1.f, (_Float16)0.f,
                    (_Float16)0.f, (_Float16)0.f, (_Float16)0.f, (_Float16)0.f};
        *(half8*)(srcfrag + (size_t)i2 * 32)      = b0;
        *(half8*)(srcfrag + (size_t)i2 * 32 + 16) = b1;
    }
}

// Kernel 1: block = 4 waves x 128 src cols = 512 src cols vs one 512-dst
// segment. Block layout: sg in bits[0:3], b in bits[4:5], srcgrp high ->
// co-resident blocks (stride 256) share one 16 KB A-slice (L1-resident).
// Per tile: 1 A-load (prefetched), 4 MFMAs (4 resident B-frags), 4 min-trees.
__global__ __launch_bounds__(TPB) void minseg_kernel(const char* __restrict__ dstfrag,
                                                     const char* __restrict__ srcfrag,
                                                     unsigned* __restrict__ minenc) {
    int l = threadIdx.x & 63;
    int wv = threadIdx.x >> 6;
    int sg = blockIdx.x & (NSEG - 1);
    int b  = (blockIdx.x >> 4) & 3;
    int srcgrp = blockIdx.x >> 6;                 // 0..15

    int mbase = (srcgrp * 4 + wv) * 128;          // this wave's 128 src cols
    int lg = l & 31, hf = (l >> 5) * 16;

    half8 bf0 = *(const half8*)(srcfrag + ((size_t)(b * NM + mbase +  0 + lg) * 32) + hf);
    half8 bf1 = *(const half8*)(srcfrag + ((size_t)(b * NM + mbase + 32 + lg) * 32) + hf);
    half8 bf2 = *(const half8*)(srcfrag + ((size_t)(b * NM + mbase + 64 + lg) * 32) + hf);
    half8 bf3 = *(const half8*)(srcfrag + ((size_t)(b * NM + mbase + 96 + lg) * 32) + hf);

    const char* aptr = dstfrag + ((size_t)(b * NN + sg * DSEG + lg) * 32) + hf;

    const f32x16 zc = {0.f,0.f,0.f,0.f,0.f,0.f,0.f,0.f,
                       0.f,0.f,0.f,0.f,0.f,0.f,0.f,0.f};
    float acc0 = 3.4e38f, acc1 = 3.4e38f, acc2 = 3.4e38f, acc3 = 3.4e38f;
    half8 af = *(const half8*)aptr;
#pragma unroll 2
    for (int j = 0; j < TILES; ++j) {
        half8 nx = (j < TILES - 1) ? *(const half8*)(aptr + (size_t)(j + 1) * 1024)
                                   : af;          // prefetch next tile
        f32x16 c0 = __builtin_amdgcn_mfma_f32_32x32x16_f16(af, bf0, zc, 0, 0, 0);
        acc0 = tile_min(c0, acc0);
        f32x16 c1 = __builtin_amdgcn_mfma_f32_32x32x16_f16(af, bf1, zc, 0, 0, 0);
        acc1 = tile_min(c1, acc1);
        f32x16 c2 = __builtin_amdgcn_mfma_f32_32x32x16_f16(af, bf2, zc, 0, 0, 0);
        acc2 = tile_min(c2, acc2);
        f32x16 c3 = __builtin_amdgcn_mfma_f32_32x32x16_f16(af, bf3, zc, 0, 0, 0);
        acc3 = tile_min(c3, acc3);
        af = nx;
    }

    acc0 = fminf(acc0, __shfl_xor(acc0, 32));     // merge lane halves
    acc1 = fminf(acc1, __shfl_xor(acc1, 32));
    acc2 = fminf(acc2, __shfl_xor(acc2, 32));
    acc3 = fminf(acc3, __shfl_xor(acc3, 32));

    int base = b * NM + mbase;
    int lo = (l < 32);
    // two atomic instrs, 64 distinct addresses each (cols: lo->0-31, hi->32-63
    // then lo->64-95, hi->96-127)
    atomicMin(&minenc[base + (lo ? lg : 32 + lg)],      enc_f32(lo ? acc0 : acc1));
    atomicMin(&minenc[base + (lo ? 64 + lg : 96 + lg)], enc_f32(lo ? acc2 : acc3));
}

// Kernel 2: per src point, d = sqrt(max(|s|^2 + minval, 0)); block tree-sum;
// deterministic fixed-point accumulate; last block (ticket) writes scalar.
__global__ __launch_bounds__(FIN_TPB) void finish_kernel(const float* __restrict__ src,
                                                         const unsigned* __restrict__ minenc,
                                                         unsigned long long* __restrict__ sumfix,
                                                         unsigned* __restrict__ ticket,
                                                         float* __restrict__ out) {
    int gm = blockIdx.x * FIN_TPB + threadIdx.x;
    int b = gm / NM, m = gm % NM;
    const float* sp = src + (size_t)b * 3 * NM;
    float x = sp[m], y = sp[NM + m], z = sp[2 * NM + m];
    float a2 = fmaf(x, x, fmaf(y, y, z * z));
    float v = dec_f32(minenc[gm]);
    float d = sqrtf(fmaxf(a2 + v, 0.0f));

    for (int off = 32; off > 0; off >>= 1) d += __shfl_down(d, off);
    __shared__ float wsum[2];
    int lane = threadIdx.x & 63, w = threadIdx.x >> 6;
    if (lane == 0) wsum[w] = d;
    __syncthreads();

    if (threadIdx.x == 0) {
        float bs = wsum[0] + wsum[1];
        // Fixed-point (32.32) accumulate: integer adds are associative ->
        // deterministic regardless of block order.
        unsigned long long inc = (unsigned long long)((double)bs * 4294967296.0);
        atomicAdd(sumfix, inc);
        __threadfence();                          // sum-add before ticket-add
        unsigned tk = atomicAdd(ticket, 1u);
        if (tk == NBLK_F - 1) {
            unsigned long long tot = atomicAdd(sumfix, 0ULL);  // coherent read
            out[0] = (float)((double)tot * (1.0 / 4294967296.0) * (1.0 / NPTS));
        }
    }
}

extern "C" void kernel_launch(void* const* d_in, const int* in_sizes, int n_in,
                              void* d_out, int out_size, void* d_ws, size_t ws_size,
                              hipStream_t stream) {
    const float* src = (const float*)d_in[0];   // [B,3,M]
    const float* dst = (const float*)d_in[1];   // [B,3,N]
    float* out = (float*)d_out;

    char* ws = (char*)d_ws;
    char* dstfrag = ws;                                              // 1 MB
    char* srcfrag = ws + (size_t)NPTS * 32;                          // 1 MB
    unsigned* minenc = (unsigned*)(ws + (size_t)NPTS * 64);          // 128 KB
    unsigned long long* sumfix =
        (unsigned long long*)(ws + (size_t)NPTS * 64 + (size_t)NPTS * 4);
    unsigned* ticket = (unsigned*)((char*)sumfix + 8);

    prep_kernel<<<(2 * NPTS) / TPB, TPB, 0, stream>>>(src, dst, dstfrag, srcfrag,
                                                      minenc, sumfix, ticket);
    minseg_kernel<<<NSEG * NB * NSRCG, TPB, 0, stream>>>(dstfrag, srcfrag, minenc);
    finish_kernel<<<NBLK_F, FIN_TPB, 0, stream>>>(src, minenc, sumfix, ticket, out);
}

// Round 13
// 27.616 us; speedup vs baseline: 1.2306x; 1.2306x over previous
//
#include <hip/hip_runtime.h>
#include <math.h>

// ChamferLoss: pc_src [B,3,M] f32, pc_dst [B,3,N] f32 -> scalar mean over (B,M)
// of min_n ||src_m - dst_n||.
//
// MFMA engine: d2p(n,m) = |d_n|^2 - 2 s_m . d_n as ONE K-column of
// v_mfma_f32_32x32x16_f16, split-f16 precision (per coord uh*sh, uh*sl,
// ul*sh with u=-2d; plus (wh,wl)*1; 11/16 K-slots; absmax 0.0 in R11/R12).
//
// R12 -> R13: structural collapse to 2 dispatches. prep kernel removed:
// A-frags for the block's 512-dst segment are built in-kernel into 16 KB
// LDS (XOR-swizzled 16B granules, both sides); B-frags built per-lane in
// registers from raw src. Atomics + memset removed: per-(seg,col) partial
// min stored plain into part[16][NPTS] (2 MB, no init); finish folds 16.
// Main loop per j: 1 swizzled ds_read_b128 + 4 MFMA + 4 min-trees; MFMA
// floor 3.4 us, VALU hides under per-SIMD MFMA issue at 4 waves/SIMD.

#define TPB 256

constexpr int NB = 4;
constexpr int NM = 8192;
constexpr int NN = 8192;
constexpr int NPTS = NB * NM;                     // 32768
constexpr int NSEG = 16;                          // dst segments
constexpr int DSEG = NN / NSEG;                   // 512 dst per segment
constexpr int TILES = DSEG / 32;                  // 16 MFMA tiles
constexpr int NSRCG = NM / 512;                   // 16 src groups (512 cols/blk)
constexpr int FIN_TPB = 128;
constexpr int NBLK_F = NPTS / FIN_TPB;            // 256 finish blocks

typedef _Float16 half8 __attribute__((ext_vector_type(8)));
typedef float f32x16 __attribute__((ext_vector_type(16)));

__device__ __forceinline__ float min3(float a, float b, float c) {
    return fminf(fminf(a, b), c);                 // -> v_min3_f32
}
__device__ __forceinline__ float tile_min(const f32x16& c, float acc) {
    float v0 = min3(c[0],  c[1],  c[2]);
    float v1 = min3(c[3],  c[4],  c[5]);
    float v2 = min3(c[6],  c[7],  c[8]);
    float v3 = min3(c[9],  c[10], c[11]);
    float v4 = min3(c[12], c[13], c[14]);
    float w0 = min3(v0, v1, c[15]);
    float w1 = min3(v2, v3, v4);
    return min3(acc, w0, w1);
}
// LDS A-frag slot for (row r, half h), 16B granules, XOR-swizzled so a
// wave's 64 reads (rows j*32+lg, half l>=32) spread across all 8 slots.
__device__ __forceinline__ int aidx(int r, int h) {
    return ((r << 1) | h) ^ ((r >> 2) & 7);
}

// Kernel 1: block = (sg, b, srcgrp): 512 src cols vs one 512-dst segment.
// Phase 1: build A-frags (dst side) into LDS + own B-frags in regs.
// Phase 2: 16 tiles x { ds_read A, 4 MFMA, 4 min-trees }.
// Store per-seg partial min (no atomics). Block 0 zeroes sum/ticket cells.
__global__ __launch_bounds__(TPB) void minseg_kernel(const float* __restrict__ src,
                                                     const float* __restrict__ dst,
                                                     float* __restrict__ part,
                                                     unsigned long long* __restrict__ sumfix,
                                                     unsigned* __restrict__ ticket) {
    __shared__ uint4 alds[DSEG * 2];              // 16 KB

    int l  = threadIdx.x & 63;
    int wv = threadIdx.x >> 6;
    int sg = blockIdx.x & (NSEG - 1);
    int b  = (blockIdx.x >> 4) & 3;
    int srcgrp = blockIdx.x >> 6;                 // 0..15

    if (blockIdx.x == 0 && threadIdx.x == 0) { *sumfix = 0ULL; *ticket = 0u; }

    // ---- Phase 1a: A-frags (dst) -> LDS, 2 rows per thread ----
    const float* pd = dst + (size_t)b * 3 * NN;
#pragma unroll
    for (int rr = 0; rr < 2; ++rr) {
        int r = threadIdx.x + rr * TPB;           // row in segment
        int n = sg * DSEG + r;
        float x = pd[n], y = pd[NN + n], z = pd[2 * NN + n];
        float ux = -2.0f * x, uy = -2.0f * y, uz = -2.0f * z;
        float w = fmaf(x, x, fmaf(y, y, z * z));
        _Float16 uhx = (_Float16)ux; _Float16 ulx = (_Float16)(ux - (float)uhx);
        _Float16 uhy = (_Float16)uy; _Float16 uly = (_Float16)(uy - (float)uhy);
        _Float16 uhz = (_Float16)uz; _Float16 ulz = (_Float16)(uz - (float)uhz);
        _Float16 wh  = (_Float16)w;  _Float16 wl  = (_Float16)(w - (float)wh);
        half8 a0 = {uhx, uhx, ulx, uhy, uhy, uly, uhz, uhz};
        half8 a1 = {ulz, wh, wl, (_Float16)0.f, (_Float16)0.f,
                    (_Float16)0.f, (_Float16)0.f, (_Float16)0.f};
        alds[aidx(r, 0)] = *(uint4*)&a0;
        alds[aidx(r, 1)] = *(uint4*)&a1;
    }

    // ---- Phase 1b: B-frags (src) in regs, 4 cols per lane ----
    int mbase = (srcgrp * 4 + wv) * 128;          // wave's 128 src cols
    int lg = l & 31;
    int hi = l >> 5;                              // 0: K0-7, 1: K8-15
    const float* ps = src + (size_t)b * 3 * NM;
    half8 bf[4];
#pragma unroll
    for (int k = 0; k < 4; ++k) {
        int c = mbase + k * 32 + lg;
        float x = ps[c], y = ps[NM + c], z = ps[2 * NM + c];
        _Float16 shx = (_Float16)x; _Float16 slx = (_Float16)(x - (float)shx);
        _Float16 shy = (_Float16)y; _Float16 sly = (_Float16)(y - (float)shy);
        _Float16 shz = (_Float16)z; _Float16 slz = (_Float16)(z - (float)shz);
        half8 b0 = {shx, slx, shx, shy, sly, shy, shz, slz};
        half8 b1 = {shz, (_Float16)1.f, (_Float16)1.f, (_Float16)0.f,
                    (_Float16)0.f, (_Float16)0.f, (_Float16)0.f, (_Float16)0.f};
        bf[k] = hi ? b1 : b0;
    }
    __syncthreads();

    // ---- Phase 2: MFMA main loop ----
    const f32x16 zc = {0.f,0.f,0.f,0.f,0.f,0.f,0.f,0.f,
                       0.f,0.f,0.f,0.f,0.f,0.f,0.f,0.f};
    float acc0 = 3.4e38f, acc1 = 3.4e38f, acc2 = 3.4e38f, acc3 = 3.4e38f;
#pragma unroll 2
    for (int j = 0; j < TILES; ++j) {
        uint4 av = alds[aidx(j * 32 + lg, hi)];
        half8 af = *(half8*)&av;
        f32x16 c0 = __builtin_amdgcn_mfma_f32_32x32x16_f16(af, bf[0], zc, 0, 0, 0);
        acc0 = tile_min(c0, acc0);
        f32x16 c1 = __builtin_amdgcn_mfma_f32_32x32x16_f16(af, bf[1], zc, 0, 0, 0);
        acc1 = tile_min(c1, acc1);
        f32x16 c2 = __builtin_amdgcn_mfma_f32_32x32x16_f16(af, bf[2], zc, 0, 0, 0);
        acc2 = tile_min(c2, acc2);
        f32x16 c3 = __builtin_amdgcn_mfma_f32_32x32x16_f16(af, bf[3], zc, 0, 0, 0);
        acc3 = tile_min(c3, acc3);
    }

    acc0 = fminf(acc0, __shfl_xor(acc0, 32));     // merge lane halves
    acc1 = fminf(acc1, __shfl_xor(acc1, 32));
    acc2 = fminf(acc2, __shfl_xor(acc2, 32));
    acc3 = fminf(acc3, __shfl_xor(acc3, 32));

    float* pp = part + (size_t)sg * NPTS + b * NM + mbase;
    int lo = (l < 32);
    pp[lo ? lg      : 32 + lg] = lo ? acc0 : acc1;   // plain stores, 1 writer
    pp[lo ? 64 + lg : 96 + lg] = lo ? acc2 : acc3;   // per cell per seg
}

// Kernel 2: per src point: min over 16 seg partials, d = sqrt(max(|s|^2+v,0));
// block tree-sum; deterministic fixed-point accumulate; last block writes out.
__global__ __launch_bounds__(FIN_TPB) void finish_kernel(const float* __restrict__ src,
                                                         const float* __restrict__ part,
                                                         unsigned long long* __restrict__ sumfix,
                                                         unsigned* __restrict__ ticket,
                                                         float* __restrict__ out) {
    int gm = blockIdx.x * FIN_TPB + threadIdx.x;
    int b = gm / NM, m = gm % NM;

    float v = fminf(part[gm], part[NPTS + gm]);
#pragma unroll
    for (int s = 2; s < NSEG; s += 2)
        v = min3(v, part[(size_t)s * NPTS + gm], part[(size_t)(s + 1) * NPTS + gm]);

    const float* sp = src + (size_t)b * 3 * NM;
    float x = sp[m], y = sp[NM + m], z = sp[2 * NM + m];
    float a2 = fmaf(x, x, fmaf(y, y, z * z));
    float d = sqrtf(fmaxf(a2 + v, 0.0f));

    for (int off = 32; off > 0; off >>= 1) d += __shfl_down(d, off);
    __shared__ float wsum[2];
    int lane = threadIdx.x & 63, w = threadIdx.x >> 6;
    if (lane == 0) wsum[w] = d;
    __syncthreads();

    if (threadIdx.x == 0) {
        float bs = wsum[0] + wsum[1];
        // Fixed-point (32.32) accumulate: integer adds are associative ->
        // deterministic regardless of block order.
        unsigned long long inc = (unsigned long long)((double)bs * 4294967296.0);
        atomicAdd(sumfix, inc);
        __threadfence();                          // sum-add before ticket-add
        unsigned tk = atomicAdd(ticket, 1u);
        if (tk == NBLK_F - 1) {
            unsigned long long tot = atomicAdd(sumfix, 0ULL);  // coherent read
            out[0] = (float)((double)tot * (1.0 / 4294967296.0) * (1.0 / NPTS));
        }
    }
}

extern "C" void kernel_launch(void* const* d_in, const int* in_sizes, int n_in,
                              void* d_out, int out_size, void* d_ws, size_t ws_size,
                              hipStream_t stream) {
    const float* src = (const float*)d_in[0];   // [B,3,M]
    const float* dst = (const float*)d_in[1];   // [B,3,N]
    float* out = (float*)d_out;

    char* ws = (char*)d_ws;
    float* part = (float*)ws;                                        // 2 MB
    unsigned long long* sumfix =
        (unsigned long long*)(ws + (size_t)NSEG * NPTS * 4);         // 8 B
    unsigned* ticket = (unsigned*)(ws + (size_t)NSEG * NPTS * 4 + 8);// 4 B

    minseg_kernel<<<NSEG * NB * NSRCG, TPB, 0, stream>>>(src, dst, part,
                                                         sumfix, ticket);
    finish_kernel<<<NBLK_F, FIN_TPB, 0, stream>>>(src, part, sumfix, ticket, out);
}